// Round 1
// baseline (692.507 us; speedup 1.0000x reference)
//
#include <hip/hip_runtime.h>
#include <hip/hip_bf16.h>
#include <math.h>

// MoE MLP, MI355X. B=2,S=2048 -> NTOK=4096 tokens, D=1024, F=4096, E=8, top2.
#define NTOK 4096
#define DD 1024
#define FF 4096
#define NEXP 8
#define BM 256
#define BN 128
#define BK 64
#define PAIR_CAP 10240   // 8192 pairs + 8*255 pad, rounded to BM
#define TILES_MAX 40     // PAIR_CAP / BM

typedef short bf16x8 __attribute__((ext_vector_type(8)));
typedef float f32x4 __attribute__((ext_vector_type(4)));

__device__ __forceinline__ ushort f2bf(float x) {
  unsigned u = __float_as_uint(x);
  unsigned r = (u + 0x7FFFu + ((u >> 16) & 1u)) >> 16;
  return (ushort)r;
}

__device__ __forceinline__ void async16(const void* g, void* l) {
  __builtin_amdgcn_global_load_lds(
      (const __attribute__((address_space(1))) char*)g,
      (__attribute__((address_space(3))) char*)l, 16, 0, 0);
}

// ---------------- small kernels ----------------

__global__ void k_convert4(const float4* __restrict__ s, ushort* __restrict__ d, int n4) {
  int i = blockIdx.x * 256 + threadIdx.x;
  if (i >= n4) return;
  float4 v = s[i];
  ushort4 o;
  o.x = f2bf(v.x); o.y = f2bf(v.y); o.z = f2bf(v.z); o.w = f2bf(v.w);
  *(ushort4*)(d + (size_t)i * 4) = o;
}

// src [E][R][C] f32 -> dst [E][C][R] bf16
__global__ void k_transpose(const float* __restrict__ src, ushort* __restrict__ dst,
                            int R, int C) {
  __shared__ float tile[32][33];
  int e = blockIdx.z;
  const float* s = src + (size_t)e * R * C;
  ushort* d = dst + (size_t)e * R * C;
  int c0 = blockIdx.x * 32, r0 = blockIdx.y * 32;
  int tx = threadIdx.x & 31, ty = threadIdx.x >> 5;  // 32 x 8
#pragma unroll
  for (int i = 0; i < 4; ++i)
    tile[ty + i * 8][tx] = s[(size_t)(r0 + ty + i * 8) * C + c0 + tx];
  __syncthreads();
#pragma unroll
  for (int i = 0; i < 4; ++i)
    d[(size_t)(c0 + ty + i * 8) * R + r0 + tx] = f2bf(tile[tx][ty + i * 8]);
}

__global__ void k_simnorm(const float* __restrict__ sim, double* __restrict__ snorm) {
  int wid = threadIdx.x >> 6, lane = threadIdx.x & 63;  // 8 waves = 8 experts
  double s = 0.0;
  for (int d = lane; d < DD; d += 64) { double v = sim[wid * DD + d]; s += v * v; }
#pragma unroll
  for (int m = 32; m; m >>= 1) s += __shfl_down(s, m);
  if (lane == 0) snorm[wid] = sqrt(s);
}

// u[e][d] = sum_o Wp[o][d]*sim[e][o] / max(||sim_e||,eps)    (f64)
__global__ void k_u(const float* __restrict__ wp, const float* __restrict__ sim,
                    const double* __restrict__ snorm, double* __restrict__ u) {
  int d = blockIdx.x * 256 + threadIdx.x;
  int e = blockIdx.y;
  double acc = 0.0;
#pragma unroll 8
  for (int o = 0; o < DD; ++o)
    acc += (double)wp[(size_t)o * DD + d] * (double)sim[e * DD + o];
  u[e * DD + d] = acc / fmax(snorm[e], 1e-12);
}

__global__ void k_nured(const float* __restrict__ part, float* __restrict__ nu) {
  int t = blockIdx.x * 256 + threadIdx.x;
  float s = 0.f;
#pragma unroll
  for (int i = 0; i < 16; ++i) s += part[t * 16 + i];
  nu[t] = s;
}

// per-token: n_e = x . u_e (f64), scores = n_e / (max(||proj||,eps)*T), top2 + softmax
__global__ void k_gate(const float* __restrict__ x, const double* __restrict__ u,
                       const float* __restrict__ nu, const float* __restrict__ temp,
                       int* __restrict__ t2e, float* __restrict__ t2p) {
  int wid = threadIdx.x >> 6, lane = threadIdx.x & 63;
  int t = blockIdx.x * 4 + wid;
  double acc[NEXP];
#pragma unroll
  for (int e = 0; e < NEXP; ++e) acc[e] = 0.0;
  for (int d = lane; d < DD; d += 64) {
    double xv = x[(size_t)t * DD + d];
#pragma unroll
    for (int e = 0; e < NEXP; ++e) acc[e] += xv * u[e * DD + d];
  }
#pragma unroll
  for (int e = 0; e < NEXP; ++e)
    for (int m = 32; m; m >>= 1) acc[e] += __shfl_down(acc[e], m);
  if (lane == 0) {
    double den = fmax(sqrt((double)nu[t]), 1e-12) * (double)temp[0];
    double s[NEXP];
#pragma unroll
    for (int e = 0; e < NEXP; ++e) s[e] = acc[e] / den;
    int e1 = 0; double v1 = s[0];
    for (int e = 1; e < NEXP; ++e) if (s[e] > v1) { v1 = s[e]; e1 = e; }
    int e2 = -1; double v2 = -1e300;
    for (int e = 0; e < NEXP; ++e) if (e != e1 && s[e] > v2) { v2 = s[e]; e2 = e; }
    double z = exp(v2 - v1);
    double inv = 1.0 / (1.0 + z);
    t2e[t * 2] = e1; t2e[t * 2 + 1] = e2;
    t2p[t * 2] = (float)inv; t2p[t * 2 + 1] = (float)(z * inv);
  }
}

// meta: [0..7]=cnt [8..16]=padded offsets [17]=ntiles [18..25]=cursors [26..]=tile_expert
__global__ void k_count(const int* __restrict__ t2e, int* __restrict__ meta,
                        int* __restrict__ ptok, float* __restrict__ pp) {
  __shared__ int cnt[NEXP];
  int tid = threadIdx.x;
  if (tid < NEXP) cnt[tid] = 0;
  __syncthreads();
  for (int i = tid; i < NTOK * 2; i += 256) atomicAdd(&cnt[t2e[i]], 1);
  __syncthreads();
  if (tid == 0) {
    int off = 0;
    for (int e = 0; e < NEXP; ++e) {
      meta[e] = cnt[e];
      meta[8 + e] = off;
      off += ((cnt[e] + BM - 1) / BM) * BM;
    }
    meta[16] = off;
    meta[17] = off / BM;
    for (int e = 0; e < NEXP; ++e) meta[18 + e] = 0;
    int ti = 0;
    for (int e = 0; e < NEXP; ++e) {
      int nt = (cnt[e] + BM - 1) / BM;
      for (int k = 0; k < nt; ++k) meta[26 + ti++] = e;
    }
  }
  for (int i = tid; i < PAIR_CAP; i += 256) { ptok[i] = 0; pp[i] = 0.f; }
}

__global__ void k_scatter(const int* __restrict__ t2e, const float* __restrict__ t2p,
                          int* __restrict__ meta, int* __restrict__ ptok,
                          float* __restrict__ pp) {
  int i = blockIdx.x * 256 + threadIdx.x;
  if (i >= NTOK * 2) return;
  int e = t2e[i];
  int slot = atomicAdd(&meta[18 + e], 1);
  int pos = meta[8 + e] + slot;
  ptok[pos] = i >> 1;
  pp[pos] = t2p[i];
}

// ---------------- GEMM: 256x128 tile, BK=64, 8 waves, dbuf LDS, 16x16x32 bf16 MFMA.
// A,B both [rows][K] bf16 row-major. EPI: 0=proj(nu) 1=h(gelu) 2=out(atomicAdd)
template <int EPI>
__launch_bounds__(512, 2)
__global__ void gemm_k(const ushort* __restrict__ Abase, const ushort* __restrict__ Bbase,
                       int K, int Brows,
                       const int* __restrict__ pair_tok, const float* __restrict__ pair_p,
                       const int* __restrict__ meta, const float* __restrict__ bias,
                       float* __restrict__ nu_part, ushort* __restrict__ hout,
                       float* __restrict__ outp, int tile0) {
  __shared__ ushort As[2][BM * BK];   // 64KB
  __shared__ ushort Bs[2][BN * BK];   // 32KB
  __shared__ int tok_s[BM];
  __shared__ float p_s[BM];

  const int tid = threadIdx.x;
  const int lane = tid & 63;
  const int wid = tid >> 6;
  const int tile = blockIdx.x + tile0;
  const int nb = blockIdx.y;

  int expert = 0;
  if constexpr (EPI != 0) {
    if (tile >= meta[17]) return;
    expert = meta[26 + tile];
    if (tid < BM) {
      int pr = tile * BM + tid;
      tok_s[tid] = pair_tok[pr];
      p_s[tid] = pair_p[pr];
    }
    __syncthreads();
  }

  const char* Ac = (const char*)Abase;
  const char* Bc = (const char*)(Bbase + (size_t)expert * Brows * K);

  // A tile = 2048 16B chunks (m = c>>3, cc = c&7); source pre-swizzled cc ^= m&7
  const char* asrc[4];
#pragma unroll
  for (int i = 0; i < 4; ++i) {
    int c = i * 512 + tid;
    int m = c >> 3, cc = c & 7;
    int arow;
    if constexpr (EPI == 1) arow = tok_s[m];
    else if constexpr (EPI == 2) arow = (tile - tile0) * BM + m;
    else arow = tile * BM + m;
    asrc[i] = Ac + (size_t)arow * K * 2 + ((cc ^ (m & 7)) << 4);
  }
  const char* bsrc[2];
#pragma unroll
  for (int i = 0; i < 2; ++i) {
    int c = i * 512 + tid;
    int n = c >> 3, cc = c & 7;
    bsrc[i] = Bc + (size_t)(nb * BN + n) * K * 2 + ((cc ^ (n & 7)) << 4);
  }

  const int wr = wid >> 1, wc = wid & 1;
  const int l15 = lane & 15, lg = lane >> 4;

  f32x4 acc[4][4];
#pragma unroll
  for (int a = 0; a < 4; ++a)
#pragma unroll
    for (int b = 0; b < 4; ++b) acc[a][b] = (f32x4){0.f, 0.f, 0.f, 0.f};

  const int nk = K / BK;

  // prologue stage -> buf 0
#pragma unroll
  for (int i = 0; i < 4; ++i)
    async16(asrc[i], (char*)(&As[0][0]) + (i * 512 + wid * 64) * 16);
#pragma unroll
  for (int i = 0; i < 2; ++i)
    async16(bsrc[i], (char*)(&Bs[0][0]) + (i * 512 + wid * 64) * 16);

  for (int kt = 0; kt < nk; ++kt) {
    const int cur = kt & 1;
    __syncthreads();  // compiler drains vmcnt before barrier -> buf[cur] ready
    if (kt + 1 < nk) {
      const size_t ko = (size_t)(kt + 1) * BK * 2;
#pragma unroll
      for (int i = 0; i < 4; ++i)
        async16(asrc[i] + ko, (char*)(&As[cur ^ 1][0]) + (i * 512 + wid * 64) * 16);
#pragma unroll
      for (int i = 0; i < 2; ++i)
        async16(bsrc[i] + ko, (char*)(&Bs[cur ^ 1][0]) + (i * 512 + wid * 64) * 16);
    }
    const char* Ab = (const char*)(&As[cur][0]);
    const char* Bb = (const char*)(&Bs[cur][0]);
#pragma unroll
    for (int kk = 0; kk < 2; ++kk) {
      bf16x8 af[4], bfr[4];
#pragma unroll
      for (int fi = 0; fi < 4; ++fi) {
        int r = wr * 64 + fi * 16 + l15;
        int cidx = (kk * 4 + lg) ^ (r & 7);
        af[fi] = *(const bf16x8*)(Ab + r * 128 + cidx * 16);
      }
#pragma unroll
      for (int fj = 0; fj < 4; ++fj) {
        int r = wc * 64 + fj * 16 + l15;
        int cidx = (kk * 4 + lg) ^ (r & 7);
        bfr[fj] = *(const bf16x8*)(Bb + r * 128 + cidx * 16);
      }
#pragma unroll
      for (int fi = 0; fi < 4; ++fi)
#pragma unroll
        for (int fj = 0; fj < 4; ++fj)
          acc[fi][fj] =
              __builtin_amdgcn_mfma_f32_16x16x32_bf16(af[fi], bfr[fj], acc[fi][fj], 0, 0, 0);
    }
  }

  if constexpr (EPI == 0) {
    // per-row sum of squares over this block's 128 cols -> nu_part[row][nb*2+wc]
#pragma unroll
    for (int fi = 0; fi < 4; ++fi) {
#pragma unroll
      for (int j = 0; j < 4; ++j) {
        float s = 0.f;
#pragma unroll
        for (int fj = 0; fj < 4; ++fj) { float v = acc[fi][fj][j]; s += v * v; }
        s += __shfl_xor(s, 1); s += __shfl_xor(s, 2);
        s += __shfl_xor(s, 4); s += __shfl_xor(s, 8);
        if (l15 == 0) {
          int row = tile * BM + wr * 64 + fi * 16 + lg * 4 + j;
          nu_part[row * 16 + nb * 2 + wc] = s;
        }
      }
    }
  } else if constexpr (EPI == 1) {
    float bv[4];
#pragma unroll
    for (int fj = 0; fj < 4; ++fj)
      bv[fj] = bias[expert * FF + nb * BN + wc * 64 + fj * 16 + l15];
#pragma unroll
    for (int fi = 0; fi < 4; ++fi)
#pragma unroll
      for (int fj = 0; fj < 4; ++fj)
#pragma unroll
        for (int j = 0; j < 4; ++j) {
          float v = acc[fi][fj][j] + bv[fj];
          float g = 0.5f * v * (1.0f + erff(v * 0.70710678118654752f));  // exact gelu
          int rl = wr * 64 + fi * 16 + lg * 4 + j;
          size_t grow = (size_t)(tile - tile0) * BM + rl;
          int col = nb * BN + wc * 64 + fj * 16 + l15;
          hout[grow * FF + col] = f2bf(g);
        }
  } else {
    float bv[4];
#pragma unroll
    for (int fj = 0; fj < 4; ++fj)
      bv[fj] = bias[expert * DD + nb * BN + wc * 64 + fj * 16 + l15];
#pragma unroll
    for (int fi = 0; fi < 4; ++fi)
#pragma unroll
      for (int j = 0; j < 4; ++j) {
        int rl = wr * 64 + fi * 16 + lg * 4 + j;
        int tok = tok_s[rl];
        float p = p_s[rl];
#pragma unroll
        for (int fj = 0; fj < 4; ++fj) {
          float v = (acc[fi][fj][j] + bv[fj]) * p;
          int col = nb * BN + wc * 64 + fj * 16 + l15;
          atomicAdd(outp + (size_t)tok * DD + col, v);  // exactly 2 real adds/elem: commutative -> deterministic
        }
      }
  }
}

// ---------------- host ----------------

extern "C" void kernel_launch(void* const* d_in, const int* in_sizes, int n_in,
                              void* d_out, int out_size, void* d_ws, size_t ws_size,
                              hipStream_t stream) {
  const float* x = (const float*)d_in[0];
  const float* wp = (const float*)d_in[1];
  const float* sim = (const float*)d_in[2];
  const float* temp = (const float*)d_in[3];
  const float* w1 = (const float*)d_in[4];
  const float* b1 = (const float*)d_in[5];
  const float* w2 = (const float*)d_in[6];
  const float* b2 = (const float*)d_in[7];
  float* out = (float*)d_out;

  char* w = (char*)d_ws;
  size_t off = 0;
  auto alloc = [&](size_t sz) {
    char* p = w + off;
    off = (off + sz + 255) & ~(size_t)255;
    return p;
  };
  double* u = (double*)alloc((size_t)NEXP * DD * 8);
  double* snorm = (double*)alloc(NEXP * 8);
  float* nu_part = (float*)alloc((size_t)NTOK * 16 * 4);
  float* nu = (float*)alloc((size_t)NTOK * 4);
  int* t2e = (int*)alloc((size_t)NTOK * 2 * 4);
  float* t2p = (float*)alloc((size_t)NTOK * 2 * 4);
  int* meta = (int*)alloc(512);
  int* ptok = (int*)alloc((size_t)PAIR_CAP * 4);
  float* pp = (float*)alloc((size_t)PAIR_CAP * 4);
  ushort* xbf = (ushort*)alloc((size_t)NTOK * DD * 2);
  ushort* wpbf = (ushort*)alloc((size_t)DD * DD * 2);
  ushort* w1t = (ushort*)alloc((size_t)NEXP * DD * FF * 2);
  ushort* w2t = (ushort*)alloc((size_t)NEXP * DD * FF * 2);
  size_t havail = (ws_size > off) ? (ws_size - off) : 0;
  int G = (int)(havail / ((size_t)BM * FF * 2));
  if (G > TILES_MAX) G = TILES_MAX;
  if (G < 1) G = 1;
  ushort* h = (ushort*)(w + off);

  hipMemsetAsync(d_out, 0, (size_t)out_size * 4, stream);

  k_convert4<<<dim3(NTOK * DD / 4 / 256), 256, 0, stream>>>((const float4*)x, xbf, NTOK * DD / 4);
  k_convert4<<<dim3(DD * DD / 4 / 256), 256, 0, stream>>>((const float4*)wp, wpbf, DD * DD / 4);
  k_transpose<<<dim3(FF / 32, DD / 32, NEXP), 256, 0, stream>>>(w1, w1t, DD, FF);
  k_transpose<<<dim3(DD / 32, FF / 32, NEXP), 256, 0, stream>>>(w2, w2t, FF, DD);
  k_simnorm<<<1, 512, 0, stream>>>(sim, snorm);
  k_u<<<dim3(DD / 256, NEXP), 256, 0, stream>>>(wp, sim, snorm, u);
  gemm_k<0><<<dim3(NTOK / BM, DD / BN), 512, 0, stream>>>(
      xbf, wpbf, DD, DD, nullptr, nullptr, nullptr, nullptr, nu_part, nullptr, nullptr, 0);
  k_nured<<<dim3(NTOK / 256), 256, 0, stream>>>(nu_part, nu);
  k_gate<<<dim3(NTOK / 4), 256, 0, stream>>>(x, u, nu, temp, t2e, t2p);
  k_count<<<1, 256, 0, stream>>>(t2e, meta, ptok, pp);
  k_scatter<<<dim3(NTOK * 2 / 256), 256, 0, stream>>>(t2e, t2p, meta, ptok, pp);

  for (int t0 = 0; t0 < TILES_MAX; t0 += G) {
    int g = TILES_MAX - t0;
    if (g > G) g = G;
    gemm_k<1><<<dim3(g, FF / BN), 512, 0, stream>>>(
        xbf, w1t, DD, FF, ptok, pp, meta, b1, nullptr, h, nullptr, t0);
    gemm_k<2><<<dim3(g, DD / BN), 512, 0, stream>>>(
        h, w2t, FF, DD, ptok, pp, meta, b2, nullptr, nullptr, out, t0);
  }
}

// Round 2
// 653.034 us; speedup vs baseline: 1.0604x; 1.0604x over previous
//
#include <hip/hip_runtime.h>
#include <hip/hip_bf16.h>
#include <math.h>

// MoE MLP, MI355X. B=2,S=2048 -> NTOK=4096 tokens, D=1024, F=4096, E=8, top2.
#define NTOK 4096
#define DD 1024
#define FF 4096
#define NEXP 8
#define BM 256
#define BN 256
#define BK 32
#define PAIR_CAP 10240   // 8192 pairs + 8*255 pad, rounded to 256
#define TILES_MAX 40     // PAIR_CAP / 256

typedef short bf16x8 __attribute__((ext_vector_type(8)));
typedef float f32x4 __attribute__((ext_vector_type(4)));

__device__ __forceinline__ ushort f2bf(float x) {
  unsigned u = __float_as_uint(x);
  unsigned r = (u + 0x7FFFu + ((u >> 16) & 1u)) >> 16;
  return (ushort)r;
}

__device__ __forceinline__ void async16(const void* g, void* l) {
  __builtin_amdgcn_global_load_lds(
      (const __attribute__((address_space(1))) char*)g,
      (__attribute__((address_space(3))) char*)l, 16, 0, 0);
}

// ---------------- small kernels ----------------

__global__ void k_convert4(const float4* __restrict__ s, ushort* __restrict__ d, int n4) {
  int i = blockIdx.x * 256 + threadIdx.x;
  if (i >= n4) return;
  float4 v = s[i];
  ushort4 o;
  o.x = f2bf(v.x); o.y = f2bf(v.y); o.z = f2bf(v.z); o.w = f2bf(v.w);
  *(ushort4*)(d + (size_t)i * 4) = o;
}

// src [E][R][C] f32 -> dst [E][C][R] bf16
__global__ void k_transpose(const float* __restrict__ src, ushort* __restrict__ dst,
                            int R, int C) {
  __shared__ float tile[32][33];
  int e = blockIdx.z;
  const float* s = src + (size_t)e * R * C;
  ushort* d = dst + (size_t)e * R * C;
  int c0 = blockIdx.x * 32, r0 = blockIdx.y * 32;
  int tx = threadIdx.x & 31, ty = threadIdx.x >> 5;  // 32 x 8
#pragma unroll
  for (int i = 0; i < 4; ++i)
    tile[ty + i * 8][tx] = s[(size_t)(r0 + ty + i * 8) * C + c0 + tx];
  __syncthreads();
#pragma unroll
  for (int i = 0; i < 4; ++i)
    d[(size_t)(c0 + ty + i * 8) * R + r0 + tx] = f2bf(tile[tx][ty + i * 8]);
}

__global__ void k_simnorm(const float* __restrict__ sim, double* __restrict__ snorm) {
  int wid = threadIdx.x >> 6, lane = threadIdx.x & 63;  // 8 waves = 8 experts
  double s = 0.0;
  for (int d = lane; d < DD; d += 64) { double v = sim[wid * DD + d]; s += v * v; }
#pragma unroll
  for (int m = 32; m; m >>= 1) s += __shfl_down(s, m);
  if (lane == 0) snorm[wid] = sqrt(s);
}

// u[e][d] = sum_o Wp[o][d]*sim[e][o] / max(||sim_e||,eps)    (f64)
__global__ void k_u(const float* __restrict__ wp, const float* __restrict__ sim,
                    const double* __restrict__ snorm, double* __restrict__ u) {
  int d = blockIdx.x * 256 + threadIdx.x;
  int e = blockIdx.y;
  double acc = 0.0;
#pragma unroll 8
  for (int o = 0; o < DD; ++o)
    acc += (double)wp[(size_t)o * DD + d] * (double)sim[e * DD + o];
  u[e * DD + d] = acc / fmax(snorm[e], 1e-12);
}

__global__ void k_nured(const float* __restrict__ part, float* __restrict__ nu) {
  int t = blockIdx.x * 256 + threadIdx.x;
  float s = 0.f;
#pragma unroll
  for (int i = 0; i < 16; ++i) s += part[t * 16 + i];
  nu[t] = s;
}

// per-token: n_e = x . u_e (f64), scores = n_e / (max(||proj||,eps)*T), top2 + softmax
__global__ void k_gate(const float* __restrict__ x, const double* __restrict__ u,
                       const float* __restrict__ nu, const float* __restrict__ temp,
                       int* __restrict__ t2e, float* __restrict__ t2p) {
  int wid = threadIdx.x >> 6, lane = threadIdx.x & 63;
  int t = blockIdx.x * 4 + wid;
  double acc[NEXP];
#pragma unroll
  for (int e = 0; e < NEXP; ++e) acc[e] = 0.0;
  for (int d = lane; d < DD; d += 64) {
    double xv = x[(size_t)t * DD + d];
#pragma unroll
    for (int e = 0; e < NEXP; ++e) acc[e] += xv * u[e * DD + d];
  }
#pragma unroll
  for (int e = 0; e < NEXP; ++e)
    for (int m = 32; m; m >>= 1) acc[e] += __shfl_down(acc[e], m);
  if (lane == 0) {
    double den = fmax(sqrt((double)nu[t]), 1e-12) * (double)temp[0];
    double s[NEXP];
#pragma unroll
    for (int e = 0; e < NEXP; ++e) s[e] = acc[e] / den;
    int e1 = 0; double v1 = s[0];
    for (int e = 1; e < NEXP; ++e) if (s[e] > v1) { v1 = s[e]; e1 = e; }
    int e2 = -1; double v2 = -1e300;
    for (int e = 0; e < NEXP; ++e) if (e != e1 && s[e] > v2) { v2 = s[e]; e2 = e; }
    double z = exp(v2 - v1);
    double inv = 1.0 / (1.0 + z);
    t2e[t * 2] = e1; t2e[t * 2 + 1] = e2;
    t2p[t * 2] = (float)inv; t2p[t * 2 + 1] = (float)(z * inv);
  }
}

// meta: [0..7]=cnt [8..16]=padded offsets [17]=ntiles [18..25]=cursors [26..]=tile_expert
__global__ void k_count(const int* __restrict__ t2e, int* __restrict__ meta,
                        int* __restrict__ ptok, float* __restrict__ pp) {
  __shared__ int cnt[NEXP];
  int tid = threadIdx.x;
  if (tid < NEXP) cnt[tid] = 0;
  __syncthreads();
  for (int i = tid; i < NTOK * 2; i += 256) atomicAdd(&cnt[t2e[i]], 1);
  __syncthreads();
  if (tid == 0) {
    int off = 0;
    for (int e = 0; e < NEXP; ++e) {
      meta[e] = cnt[e];
      meta[8 + e] = off;
      off += ((cnt[e] + 255) / 256) * 256;
    }
    meta[16] = off;
    meta[17] = off / 256;
    for (int e = 0; e < NEXP; ++e) meta[18 + e] = 0;
    int ti = 0;
    for (int e = 0; e < NEXP; ++e) {
      int nt = (cnt[e] + 255) / 256;
      for (int k = 0; k < nt; ++k) meta[26 + ti++] = e;
    }
  }
  for (int i = tid; i < PAIR_CAP; i += 256) { ptok[i] = 0; pp[i] = 0.f; }
}

__global__ void k_scatter(const int* __restrict__ t2e, const float* __restrict__ t2p,
                          int* __restrict__ meta, int* __restrict__ ptok,
                          float* __restrict__ pp) {
  int i = blockIdx.x * 256 + threadIdx.x;
  if (i >= NTOK * 2) return;
  int e = t2e[i];
  int slot = atomicAdd(&meta[18 + e], 1);
  int pos = meta[8 + e] + slot;
  ptok[pos] = i >> 1;
  pp[pos] = t2p[i];
}

// ---------------- proj GEMM (verified old structure): 256x128 tile, BK=64,
// 8 waves 4x2, dbuf LDS, epilogue = per-row sum of squares -> nu_part.
__launch_bounds__(512, 2)
__global__ void gemm_proj(const ushort* __restrict__ Abase, const ushort* __restrict__ Bbase,
                          int K, float* __restrict__ nu_part) {
  __shared__ ushort As[2][256 * 64];
  __shared__ ushort Bs[2][128 * 64];

  const int tid = threadIdx.x;
  const int lane = tid & 63;
  const int wid = tid >> 6;
  const int tile = blockIdx.x;
  const int nb = blockIdx.y;

  const char* Ac = (const char*)Abase;
  const char* Bc = (const char*)Bbase;

  const char* asrc[4];
#pragma unroll
  for (int i = 0; i < 4; ++i) {
    int c = i * 512 + tid;
    int m = c >> 3, cc = c & 7;
    int arow = tile * 256 + m;
    asrc[i] = Ac + (size_t)arow * K * 2 + ((cc ^ (m & 7)) << 4);
  }
  const char* bsrc[2];
#pragma unroll
  for (int i = 0; i < 2; ++i) {
    int c = i * 512 + tid;
    int n = c >> 3, cc = c & 7;
    bsrc[i] = Bc + (size_t)(nb * 128 + n) * K * 2 + ((cc ^ (n & 7)) << 4);
  }

  const int wr = wid >> 1, wc = wid & 1;
  const int l15 = lane & 15, lg = lane >> 4;

  f32x4 acc[4][4];
#pragma unroll
  for (int a = 0; a < 4; ++a)
#pragma unroll
    for (int b = 0; b < 4; ++b) acc[a][b] = (f32x4){0.f, 0.f, 0.f, 0.f};

  const int nk = K / 64;

#pragma unroll
  for (int i = 0; i < 4; ++i)
    async16(asrc[i], (char*)(&As[0][0]) + (i * 512 + wid * 64) * 16);
#pragma unroll
  for (int i = 0; i < 2; ++i)
    async16(bsrc[i], (char*)(&Bs[0][0]) + (i * 512 + wid * 64) * 16);

  for (int kt = 0; kt < nk; ++kt) {
    const int cur = kt & 1;
    __syncthreads();
    if (kt + 1 < nk) {
      const size_t ko = (size_t)(kt + 1) * 128;
#pragma unroll
      for (int i = 0; i < 4; ++i)
        async16(asrc[i] + ko, (char*)(&As[cur ^ 1][0]) + (i * 512 + wid * 64) * 16);
#pragma unroll
      for (int i = 0; i < 2; ++i)
        async16(bsrc[i] + ko, (char*)(&Bs[cur ^ 1][0]) + (i * 512 + wid * 64) * 16);
    }
    const char* Ab = (const char*)(&As[cur][0]);
    const char* Bb = (const char*)(&Bs[cur][0]);
#pragma unroll
    for (int kk = 0; kk < 2; ++kk) {
      bf16x8 af[4], bfr[4];
#pragma unroll
      for (int fi = 0; fi < 4; ++fi) {
        int r = wr * 64 + fi * 16 + l15;
        int cidx = (kk * 4 + lg) ^ (r & 7);
        af[fi] = *(const bf16x8*)(Ab + r * 128 + cidx * 16);
      }
#pragma unroll
      for (int fj = 0; fj < 4; ++fj) {
        int r = wc * 64 + fj * 16 + l15;
        int cidx = (kk * 4 + lg) ^ (r & 7);
        bfr[fj] = *(const bf16x8*)(Bb + r * 128 + cidx * 16);
      }
#pragma unroll
      for (int fi = 0; fi < 4; ++fi)
#pragma unroll
        for (int fj = 0; fj < 4; ++fj)
          acc[fi][fj] =
              __builtin_amdgcn_mfma_f32_16x16x32_bf16(af[fi], bfr[fj], acc[fi][fj], 0, 0, 0);
    }
  }

#pragma unroll
  for (int fi = 0; fi < 4; ++fi) {
#pragma unroll
    for (int j = 0; j < 4; ++j) {
      float s = 0.f;
#pragma unroll
      for (int fj = 0; fj < 4; ++fj) { float v = acc[fi][fj][j]; s += v * v; }
      s += __shfl_xor(s, 1); s += __shfl_xor(s, 2);
      s += __shfl_xor(s, 4); s += __shfl_xor(s, 8);
      if (l15 == 0) {
        int row = tile * 256 + wr * 64 + fi * 16 + lg * 4 + j;
        nu_part[row * 16 + nb * 2 + wc] = s;
      }
    }
  }
}

// ---------------- expert GEMM: 256x256 tile, BK=32, 8 waves (2Mx4N, each 128x64),
// triple-buffered LDS, 2 phases per K-tile, counted vmcnt(4), raw barriers, setprio.
// A,B both [rows][K] bf16 row-major, pre-swizzled chunk source (mod-4 XOR).
// EPI: 1 = gather-x @ W1^T + bias + gelu -> h(bf16); 2 = h @ W2^T + bias, *p, atomicAdd out.
template <int EPI>
__launch_bounds__(512, 2)
__global__ void gemm_x(const ushort* __restrict__ Abase, const ushort* __restrict__ Bbase,
                       int K, int Brows,
                       const int* __restrict__ pair_tok, const float* __restrict__ pair_p,
                       const int* __restrict__ meta, const float* __restrict__ bias,
                       ushort* __restrict__ hout, float* __restrict__ outp, int tile0) {
  __shared__ ushort As[3][BM * BK];   // 3 x 16KB
  __shared__ ushort Bs[3][BN * BK];   // 3 x 16KB
  __shared__ int tok_s[BM];
  __shared__ float p_s[BM];

  const int tid = threadIdx.x;
  const int lane = tid & 63;
  const int wid = tid >> 6;
  const int tile = blockIdx.x + tile0;
  const int nb = blockIdx.y;

  if (tile >= meta[17]) return;
  const int expert = meta[26 + tile];
  if (tid < BM) {
    int pr = tile * BM + tid;
    tok_s[tid] = pair_tok[pr];
    p_s[tid] = pair_p[pr];
  }
  __syncthreads();

  const char* Ac = (const char*)Abase;
  const char* Bc = (const char*)(Bbase + (size_t)expert * Brows * K);

  // staging: per K-tile, A = 1024 chunks of 16B (2 groups of 512), B same.
  // chunk c in group g: r = g*128 + (tid>>2), cc = tid&3; source pre-swizzled cc ^= r&3.
  const int rr = tid >> 2, c4 = tid & 3;
  const int sw = (c4 ^ (rr & 3)) << 4;
  const char* agp[2];
  const char* bgp[2];
#pragma unroll
  for (int g = 0; g < 2; ++g) {
    int rA = g * 128 + rr;
    int arow;
    if constexpr (EPI == 1) arow = tok_s[rA];
    else arow = (tile - tile0) * BM + rA;
    agp[g] = Ac + (size_t)arow * K * 2 + sw;
    bgp[g] = Bc + (size_t)(nb * BN + g * 128 + rr) * K * 2 + sw;
  }

  const int wr = wid >> 2, wc = wid & 3;   // 2 x 4 waves, each 128x64 of C
  const int l15 = lane & 15, lg = lane >> 4;
  const int slot = lg ^ (l15 & 3);

  char* AsB = (char*)(&As[0][0]);
  char* BsB = (char*)(&Bs[0][0]);
  const int aoffL = (wr * 128 + l15) * 64 + slot * 16;  // + fi*1024 + buf*16384
  const int boffL = (wc * 64 + l15) * 64 + slot * 16;   // + fj*1024 + buf*16384
  const int dstL = wid * 1024;                          // + g*8192 + buf*16384

  f32x4 acc[8][4];
#pragma unroll
  for (int a = 0; a < 8; ++a)
#pragma unroll
    for (int b = 0; b < 4; ++b) acc[a][b] = (f32x4){0.f, 0.f, 0.f, 0.f};

  const int nk = K / BK;   // >= 2 always here (32 or 128)

  // prologue: stage tiles 0 (buf0) and 1 (buf1); 4 loads each, order: per tile A0,B0,A1,B1
#pragma unroll
  for (int t = 0; t < 2; ++t) {
#pragma unroll
    for (int g = 0; g < 2; ++g) {
      async16(agp[g] + t * 64, AsB + t * 16384 + g * 8192 + dstL);
      async16(bgp[g] + t * 64, BsB + t * 16384 + g * 8192 + dstL);
    }
  }
  asm volatile("s_waitcnt vmcnt(4)" ::: "memory");   // tile 0 landed
  __builtin_amdgcn_s_barrier();
  asm volatile("" ::: "memory");

  int b0 = 0, b1 = 1, b2 = 2;
  for (int t = 0; t < nk; ++t) {
    const char* Ab = AsB + b0 * 16384;
    const char* Bb = BsB + b0 * 16384;
    char* A2 = AsB + b2 * 16384;
    char* B2 = BsB + b2 * 16384;
    const size_t ko = (size_t)(t + 2) * 64;
    const bool st = (t + 2 < nk);

    // ---------- phase A: read af[0..3] + bf[0..3], stage A-groups of t+2 ----------
    bf16x8 bfr[4], af[4];
#pragma unroll
    for (int fj = 0; fj < 4; ++fj) bfr[fj] = *(const bf16x8*)(Bb + boffL + fj * 1024);
#pragma unroll
    for (int fi = 0; fi < 4; ++fi) af[fi] = *(const bf16x8*)(Ab + aoffL + fi * 1024);
    if (st) {
      async16(agp[0] + ko, A2 + dstL);
      async16(agp[1] + ko, A2 + 8192 + dstL);
    }
    __builtin_amdgcn_s_barrier();
    asm volatile("s_waitcnt lgkmcnt(0)" ::: "memory");
    __builtin_amdgcn_sched_barrier(0);
    __builtin_amdgcn_s_setprio(1);
#pragma unroll
    for (int fi = 0; fi < 4; ++fi)
#pragma unroll
      for (int fj = 0; fj < 4; ++fj)
        acc[fi][fj] =
            __builtin_amdgcn_mfma_f32_16x16x32_bf16(af[fi], bfr[fj], acc[fi][fj], 0, 0, 0);
    __builtin_amdgcn_s_setprio(0);
    __builtin_amdgcn_sched_barrier(0);
    __builtin_amdgcn_s_barrier();
    asm volatile("" ::: "memory");

    // ---------- phase B: read af[4..7], stage B-groups of t+2, publish tile t+1 ----------
    bf16x8 af2[4];
#pragma unroll
    for (int fi = 0; fi < 4; ++fi) af2[fi] = *(const bf16x8*)(Ab + aoffL + (4 + fi) * 1024);
    if (st) {
      async16(bgp[0] + ko, B2 + dstL);
      async16(bgp[1] + ko, B2 + 8192 + dstL);
      asm volatile("s_waitcnt vmcnt(4)" ::: "memory");   // all of tile t+1 landed
    } else {
      asm volatile("s_waitcnt vmcnt(0)" ::: "memory");
    }
    __builtin_amdgcn_s_barrier();
    asm volatile("s_waitcnt lgkmcnt(0)" ::: "memory");
    __builtin_amdgcn_sched_barrier(0);
    __builtin_amdgcn_s_setprio(1);
#pragma unroll
    for (int fi = 0; fi < 4; ++fi)
#pragma unroll
      for (int fj = 0; fj < 4; ++fj)
        acc[4 + fi][fj] =
            __builtin_amdgcn_mfma_f32_16x16x32_bf16(af2[fi], bfr[fj], acc[4 + fi][fj], 0, 0, 0);
    __builtin_amdgcn_s_setprio(0);
    __builtin_amdgcn_sched_barrier(0);
    __builtin_amdgcn_s_barrier();
    asm volatile("" ::: "memory");

    int tmp = b0; b0 = b1; b1 = b2; b2 = tmp;
  }

  // ---------------- epilogue ----------------
  if constexpr (EPI == 1) {
    float bv[4];
#pragma unroll
    for (int fj = 0; fj < 4; ++fj)
      bv[fj] = bias[expert * FF + nb * BN + wc * 64 + fj * 16 + l15];
#pragma unroll
    for (int fi = 0; fi < 8; ++fi)
#pragma unroll
      for (int fj = 0; fj < 4; ++fj)
#pragma unroll
        for (int j = 0; j < 4; ++j) {
          float v = acc[fi][fj][j] + bv[fj];
          float g = 0.5f * v * (1.0f + erff(v * 0.70710678118654752f));  // exact gelu
          int rl = wr * 128 + fi * 16 + lg * 4 + j;
          size_t grow = (size_t)(tile - tile0) * BM + rl;
          int col = nb * BN + wc * 64 + fj * 16 + l15;
          hout[grow * FF + col] = f2bf(g);
        }
  } else {
    float bv[4];
#pragma unroll
    for (int fj = 0; fj < 4; ++fj)
      bv[fj] = bias[expert * DD + nb * BN + wc * 64 + fj * 16 + l15];
#pragma unroll
    for (int fi = 0; fi < 8; ++fi) {
      int rl = wr * 128 + fi * 16 + lg * 4;
#pragma unroll
      for (int j = 0; j < 4; ++j) {
        int tok = tok_s[rl + j];
        float p = p_s[rl + j];
#pragma unroll
        for (int fj = 0; fj < 4; ++fj) {
          float v = (acc[fi][fj][j] + bv[fj]) * p;
          int col = nb * BN + wc * 64 + fj * 16 + l15;
          atomicAdd(outp + (size_t)tok * DD + col, v);  // exactly 2 adds/elem (commutative -> deterministic)
        }
      }
    }
  }
}

// ---------------- host ----------------

extern "C" void kernel_launch(void* const* d_in, const int* in_sizes, int n_in,
                              void* d_out, int out_size, void* d_ws, size_t ws_size,
                              hipStream_t stream) {
  const float* x = (const float*)d_in[0];
  const float* wp = (const float*)d_in[1];
  const float* sim = (const float*)d_in[2];
  const float* temp = (const float*)d_in[3];
  const float* w1 = (const float*)d_in[4];
  const float* b1 = (const float*)d_in[5];
  const float* w2 = (const float*)d_in[6];
  const float* b2 = (const float*)d_in[7];
  float* out = (float*)d_out;

  char* w = (char*)d_ws;
  size_t off = 0;
  auto alloc = [&](size_t sz) {
    char* p = w + off;
    off = (off + sz + 255) & ~(size_t)255;
    return p;
  };
  double* u = (double*)alloc((size_t)NEXP * DD * 8);
  double* snorm = (double*)alloc(NEXP * 8);
  float* nu_part = (float*)alloc((size_t)NTOK * 16 * 4);
  float* nu = (float*)alloc((size_t)NTOK * 4);
  int* t2e = (int*)alloc((size_t)NTOK * 2 * 4);
  float* t2p = (float*)alloc((size_t)NTOK * 2 * 4);
  int* meta = (int*)alloc(512);
  int* ptok = (int*)alloc((size_t)PAIR_CAP * 4);
  float* pp = (float*)alloc((size_t)PAIR_CAP * 4);
  ushort* xbf = (ushort*)alloc((size_t)NTOK * DD * 2);
  ushort* wpbf = (ushort*)alloc((size_t)DD * DD * 2);
  ushort* w1t = (ushort*)alloc((size_t)NEXP * DD * FF * 2);
  ushort* w2t = (ushort*)alloc((size_t)NEXP * DD * FF * 2);
  size_t havail = (ws_size > off) ? (ws_size - off) : 0;
  int G = (int)(havail / ((size_t)256 * FF * 2));
  if (G > TILES_MAX) G = TILES_MAX;
  if (G < 1) G = 1;
  ushort* h = (ushort*)(w + off);

  hipMemsetAsync(d_out, 0, (size_t)out_size * 4, stream);

  k_convert4<<<dim3(NTOK * DD / 4 / 256), 256, 0, stream>>>((const float4*)x, xbf, NTOK * DD / 4);
  k_convert4<<<dim3(DD * DD / 4 / 256), 256, 0, stream>>>((const float4*)wp, wpbf, DD * DD / 4);
  k_transpose<<<dim3(FF / 32, DD / 32, NEXP), 256, 0, stream>>>(w1, w1t, DD, FF);
  k_transpose<<<dim3(DD / 32, FF / 32, NEXP), 256, 0, stream>>>(w2, w2t, FF, DD);
  k_simnorm<<<1, 512, 0, stream>>>(sim, snorm);
  k_u<<<dim3(DD / 256, NEXP), 256, 0, stream>>>(wp, sim, snorm, u);
  gemm_proj<<<dim3(NTOK / 256, DD / 128), 512, 0, stream>>>(xbf, wpbf, DD, nu_part);
  k_nured<<<dim3(NTOK / 256), 256, 0, stream>>>(nu_part, nu);
  k_gate<<<dim3(NTOK / 4), 256, 0, stream>>>(x, u, nu, temp, t2e, t2p);
  k_count<<<1, 256, 0, stream>>>(t2e, meta, ptok, pp);
  k_scatter<<<dim3(NTOK * 2 / 256), 256, 0, stream>>>(t2e, t2p, meta, ptok, pp);

  for (int t0 = 0; t0 < TILES_MAX; t0 += G) {
    int g = TILES_MAX - t0;
    if (g > G) g = G;
    gemm_x<1><<<dim3(g, FF / BN), 512, 0, stream>>>(
        xbf, w1t, DD, FF, ptok, pp, meta, b1, h, nullptr, t0);
    gemm_x<2><<<dim3(g, DD / BN), 512, 0, stream>>>(
        h, w2t, FF, DD, ptok, pp, meta, b2, nullptr, out, t0);
  }
}

// Round 3
// 631.585 us; speedup vs baseline: 1.0965x; 1.0340x over previous
//
#include <hip/hip_runtime.h>
#include <hip/hip_bf16.h>
#include <math.h>

// MoE MLP, MI355X. B=2,S=2048 -> NTOK=4096 tokens, D=1024, F=4096, E=8, top2.
#define NTOK 4096
#define DD 1024
#define FF 4096
#define NEXP 8
#define EBM 128          // expert-GEMM tile M
#define EBN 128          // expert-GEMM tile N
#define EBK 64           // expert-GEMM K-step
#define PAIR_CAP 9216    // 8192 pairs + 8*127 pad, rounded to 128
#define TILES_MAX 72     // PAIR_CAP / 128

typedef short bf16x8 __attribute__((ext_vector_type(8)));
typedef float f32x4 __attribute__((ext_vector_type(4)));

__device__ __forceinline__ ushort f2bf(float x) {
  unsigned u = __float_as_uint(x);
  unsigned r = (u + 0x7FFFu + ((u >> 16) & 1u)) >> 16;
  return (ushort)r;
}

__device__ __forceinline__ void async16(const void* g, void* l) {
  __builtin_amdgcn_global_load_lds(
      (const __attribute__((address_space(1))) char*)g,
      (__attribute__((address_space(3))) char*)l, 16, 0, 0);
}

// ---------------- small kernels ----------------

__global__ void k_convert4(const float4* __restrict__ s, ushort* __restrict__ d, int n4) {
  int i = blockIdx.x * 256 + threadIdx.x;
  if (i >= n4) return;
  float4 v = s[i];
  ushort4 o;
  o.x = f2bf(v.x); o.y = f2bf(v.y); o.z = f2bf(v.z); o.w = f2bf(v.w);
  *(ushort4*)(d + (size_t)i * 4) = o;
}

// src [E][R][C] f32 -> dst [E][C][R] bf16. 64x64 tiles, float4 in, ushort4 out.
__global__ void k_transpose(const float* __restrict__ src, ushort* __restrict__ dst,
                            int R, int C) {
  __shared__ float tile[64][65];
  int e = blockIdx.z;
  const float* s = src + (size_t)e * R * C;
  ushort* d = dst + (size_t)e * R * C;
  int c0 = blockIdx.x * 64, r0 = blockIdx.y * 64;
  int tid = threadIdx.x;           // 256
  int rr = tid >> 4, q4 = (tid & 15) * 4;
#pragma unroll
  for (int i = 0; i < 4; ++i) {
    int r = i * 16 + rr;
    float4 v = *(const float4*)&s[(size_t)(r0 + r) * C + c0 + q4];
    tile[r][q4 + 0] = v.x; tile[r][q4 + 1] = v.y;
    tile[r][q4 + 2] = v.z; tile[r][q4 + 3] = v.w;
  }
  __syncthreads();
#pragma unroll
  for (int i = 0; i < 4; ++i) {
    int c = i * 16 + rr;
    ushort4 o;
    o.x = f2bf(tile[q4 + 0][c]); o.y = f2bf(tile[q4 + 1][c]);
    o.z = f2bf(tile[q4 + 2][c]); o.w = f2bf(tile[q4 + 3][c]);
    *(ushort4*)&d[(size_t)(c0 + c) * R + r0 + q4] = o;
  }
}

__global__ void k_simnorm(const float* __restrict__ sim, double* __restrict__ snorm) {
  int wid = threadIdx.x >> 6, lane = threadIdx.x & 63;  // 8 waves = 8 experts
  double s = 0.0;
  for (int d = lane; d < DD; d += 64) { double v = sim[wid * DD + d]; s += v * v; }
#pragma unroll
  for (int m = 32; m; m >>= 1) s += __shfl_down(s, m);
  if (lane == 0) snorm[wid] = sqrt(s);
}

// u[e][d] = sum_o Wp[o][d]*sim[e][o] / max(||sim_e||,eps)    (f64)
__global__ void k_u(const float* __restrict__ wp, const float* __restrict__ sim,
                    const double* __restrict__ snorm, double* __restrict__ u) {
  int d = blockIdx.x * 256 + threadIdx.x;
  int e = blockIdx.y;
  double acc = 0.0;
#pragma unroll 8
  for (int o = 0; o < DD; ++o)
    acc += (double)wp[(size_t)o * DD + d] * (double)sim[e * DD + o];
  u[e * DD + d] = acc / fmax(snorm[e], 1e-12);
}

__global__ void k_nured(const float* __restrict__ part, float* __restrict__ nu) {
  int t = blockIdx.x * 256 + threadIdx.x;
  float s = 0.f;
#pragma unroll
  for (int i = 0; i < 16; ++i) s += part[t * 16 + i];
  nu[t] = s;
}

// per-token: n_e = x . u_e (f64), scores = n_e / (max(||proj||,eps)*T), top2 + softmax
__global__ void k_gate(const float* __restrict__ x, const double* __restrict__ u,
                       const float* __restrict__ nu, const float* __restrict__ temp,
                       int* __restrict__ t2e, float* __restrict__ t2p) {
  int wid = threadIdx.x >> 6, lane = threadIdx.x & 63;
  int t = blockIdx.x * 4 + wid;
  double acc[NEXP];
#pragma unroll
  for (int e = 0; e < NEXP; ++e) acc[e] = 0.0;
  for (int d = lane; d < DD; d += 64) {
    double xv = x[(size_t)t * DD + d];
#pragma unroll
    for (int e = 0; e < NEXP; ++e) acc[e] += xv * u[e * DD + d];
  }
#pragma unroll
  for (int e = 0; e < NEXP; ++e)
    for (int m = 32; m; m >>= 1) acc[e] += __shfl_down(acc[e], m);
  if (lane == 0) {
    double den = fmax(sqrt((double)nu[t]), 1e-12) * (double)temp[0];
    double s[NEXP];
#pragma unroll
    for (int e = 0; e < NEXP; ++e) s[e] = acc[e] / den;
    int e1 = 0; double v1 = s[0];
    for (int e = 1; e < NEXP; ++e) if (s[e] > v1) { v1 = s[e]; e1 = e; }
    int e2 = -1; double v2 = -1e300;
    for (int e = 0; e < NEXP; ++e) if (e != e1 && s[e] > v2) { v2 = s[e]; e2 = e; }
    double z = exp(v2 - v1);
    double inv = 1.0 / (1.0 + z);
    t2e[t * 2] = e1; t2e[t * 2 + 1] = e2;
    t2p[t * 2] = (float)inv; t2p[t * 2 + 1] = (float)(z * inv);
  }
}

// meta: [0..7]=cnt [8..16]=padded offsets [17]=ntiles [18..25]=cursors [26..]=tile_expert
__global__ void k_count(const int* __restrict__ t2e, int* __restrict__ meta,
                        int* __restrict__ ptok, float* __restrict__ pp) {
  __shared__ int cnt[NEXP];
  int tid = threadIdx.x;
  if (tid < NEXP) cnt[tid] = 0;
  __syncthreads();
  for (int i = tid; i < NTOK * 2; i += 256) atomicAdd(&cnt[t2e[i]], 1);
  __syncthreads();
  if (tid == 0) {
    int off = 0;
    for (int e = 0; e < NEXP; ++e) {
      meta[e] = cnt[e];
      meta[8 + e] = off;
      off += ((cnt[e] + EBM - 1) / EBM) * EBM;
    }
    meta[16] = off;
    meta[17] = off / EBM;
    for (int e = 0; e < NEXP; ++e) meta[18 + e] = 0;
    int ti = 0;
    for (int e = 0; e < NEXP; ++e) {
      int nt = (cnt[e] + EBM - 1) / EBM;
      for (int k = 0; k < nt; ++k) meta[26 + ti++] = e;
    }
  }
  for (int i = tid; i < PAIR_CAP; i += 256) { ptok[i] = 0; pp[i] = 0.f; }
}

__global__ void k_scatter(const int* __restrict__ t2e, const float* __restrict__ t2p,
                          int* __restrict__ meta, int* __restrict__ ptok,
                          float* __restrict__ pp) {
  int i = blockIdx.x * 256 + threadIdx.x;
  if (i >= NTOK * 2) return;
  int e = t2e[i];
  int slot = atomicAdd(&meta[18 + e], 1);
  int pos = meta[8 + e] + slot;
  ptok[pos] = i >> 1;
  pp[pos] = t2p[i];
}

// ---------------- unified GEMM: m97 structure. 128x128 tile, BK=64, 4 waves (2x2,
// each 64x64 out), double-buffered 64KB LDS, global_load_lds(16), 2-barrier K-loop,
// 8-chunk XOR swizzle (pre-swizzled global source, conflict-free ds_read_b128).
// A,B both [rows][K] bf16 row-major.
// EPI 0: proj -> per-row sum-of-squares into nu_part   (A=xbf, B=wpbf)
// EPI 1: gather-x @ W1t + b1, exact gelu -> h (bf16)   (A=xbf gathered, B=W1t[e])
// EPI 2: h @ W2t + b2, *p, atomicAdd into out          (A=h,  B=W2t[e])
template <int EPI>
__launch_bounds__(256, 2)
__global__ void gemm_x(const ushort* __restrict__ Abase, const ushort* __restrict__ Bbase,
                       int K, int Brows,
                       const int* __restrict__ pair_tok, const float* __restrict__ pair_p,
                       const int* __restrict__ meta, const float* __restrict__ bias,
                       float* __restrict__ nu_part, ushort* __restrict__ hout,
                       float* __restrict__ outp, int tile0) {
  __shared__ ushort As[2][EBM * EBK];   // 2 x 16KB
  __shared__ ushort Bs[2][EBN * EBK];   // 2 x 16KB
  __shared__ int tok_s[EBM];
  __shared__ float p_s[EBM];

  const int tid = threadIdx.x;          // 256
  const int lane = tid & 63;
  const int wid = tid >> 6;             // 4 waves
  const int tile = blockIdx.x + tile0;
  const int nb = blockIdx.y;

  int expert = 0;
  if constexpr (EPI != 0) {
    if (tile >= meta[17]) return;
    expert = meta[26 + tile];
    if (tid < EBM) {
      int pr = tile * EBM + tid;
      tok_s[tid] = pair_tok[pr];
      p_s[tid] = pair_p[pr];
    }
    __syncthreads();
  }

  const char* Ac = (const char*)Abase;
  const char* Bc = (const char*)(Bbase + (size_t)expert * Brows * K);

  // tile = 1024 chunks of 16B; 4 groups of 256. chunk c: m=c>>3, cc=c&7.
  // global source pre-swizzled: cc ^= m&7  (LDS stays linear -> gload_lds legal).
  const char* asrc[4];
  const char* bsrc[4];
#pragma unroll
  for (int i = 0; i < 4; ++i) {
    int m = i * 32 + (tid >> 3), cc = tid & 7;
    int sw = (cc ^ (m & 7)) << 4;
    int arow;
    if constexpr (EPI == 1) arow = tok_s[m];
    else if constexpr (EPI == 2) arow = (tile - tile0) * EBM + m;
    else arow = tile * EBM + m;
    asrc[i] = Ac + (size_t)arow * K * 2 + sw;
    bsrc[i] = Bc + (size_t)(nb * EBN + m) * K * 2 + sw;
  }

  const int wr = wid >> 1, wc = wid & 1;     // 2x2 waves, each 64x64 of C
  const int l15 = lane & 15, lg = lane >> 4;

  f32x4 acc[4][4];
#pragma unroll
  for (int a = 0; a < 4; ++a)
#pragma unroll
    for (int b = 0; b < 4; ++b) acc[a][b] = (f32x4){0.f, 0.f, 0.f, 0.f};

  const int nk = K / EBK;

  // prologue stage -> buf 0   (dest = wave-uniform base; lanes append *16)
#pragma unroll
  for (int i = 0; i < 4; ++i) {
    async16(asrc[i], (char*)(&As[0][0]) + (i * 256 + wid * 64) * 16);
    async16(bsrc[i], (char*)(&Bs[0][0]) + (i * 256 + wid * 64) * 16);
  }

  for (int kt = 0; kt < nk; ++kt) {
    const int cur = kt & 1;
    __syncthreads();  // compiler drains vmcnt before barrier -> buf[cur] ready
    if (kt + 1 < nk) {
      const size_t ko = (size_t)(kt + 1) * EBK * 2;
#pragma unroll
      for (int i = 0; i < 4; ++i) {
        async16(asrc[i] + ko, (char*)(&As[cur ^ 1][0]) + (i * 256 + wid * 64) * 16);
        async16(bsrc[i] + ko, (char*)(&Bs[cur ^ 1][0]) + (i * 256 + wid * 64) * 16);
      }
    }
    const char* Ab = (const char*)(&As[cur][0]);
    const char* Bb = (const char*)(&Bs[cur][0]);
#pragma unroll
    for (int kk = 0; kk < 2; ++kk) {
      bf16x8 af[4], bfr[4];
#pragma unroll
      for (int fi = 0; fi < 4; ++fi) {
        int r = wr * 64 + fi * 16 + l15;
        int cidx = (kk * 4 + lg) ^ (l15 & 7);
        af[fi] = *(const bf16x8*)(Ab + r * 128 + cidx * 16);
      }
#pragma unroll
      for (int fj = 0; fj < 4; ++fj) {
        int r = wc * 64 + fj * 16 + l15;
        int cidx = (kk * 4 + lg) ^ (l15 & 7);
        bfr[fj] = *(const bf16x8*)(Bb + r * 128 + cidx * 16);
      }
#pragma unroll
      for (int fi = 0; fi < 4; ++fi)
#pragma unroll
        for (int fj = 0; fj < 4; ++fj)
          acc[fi][fj] =
              __builtin_amdgcn_mfma_f32_16x16x32_bf16(af[fi], bfr[fj], acc[fi][fj], 0, 0, 0);
    }
  }

  // ---------------- epilogue ----------------
  if constexpr (EPI == 0) {
    // per-row sum of squares over this block's 128 cols -> nu_part[row][nb*2+wc]
#pragma unroll
    for (int fi = 0; fi < 4; ++fi) {
#pragma unroll
      for (int j = 0; j < 4; ++j) {
        float s = 0.f;
#pragma unroll
        for (int fj = 0; fj < 4; ++fj) { float v = acc[fi][fj][j]; s += v * v; }
        s += __shfl_xor(s, 1); s += __shfl_xor(s, 2);
        s += __shfl_xor(s, 4); s += __shfl_xor(s, 8);
        if (l15 == 0) {
          int row = tile * EBM + wr * 64 + fi * 16 + lg * 4 + j;
          nu_part[row * 16 + nb * 2 + wc] = s;
        }
      }
    }
  } else if constexpr (EPI == 1) {
    float bv[4];
#pragma unroll
    for (int fj = 0; fj < 4; ++fj)
      bv[fj] = bias[expert * FF + nb * EBN + wc * 64 + fj * 16 + l15];
#pragma unroll
    for (int fi = 0; fi < 4; ++fi)
#pragma unroll
      for (int fj = 0; fj < 4; ++fj)
#pragma unroll
        for (int j = 0; j < 4; ++j) {
          float v = acc[fi][fj][j] + bv[fj];
          float g = 0.5f * v * (1.0f + erff(v * 0.70710678118654752f));  // exact gelu
          int rl = wr * 64 + fi * 16 + lg * 4 + j;
          size_t grow = (size_t)(tile - tile0) * EBM + rl;
          int col = nb * EBN + wc * 64 + fj * 16 + l15;
          hout[grow * FF + col] = f2bf(g);
        }
  } else {
    float bv[4];
#pragma unroll
    for (int fj = 0; fj < 4; ++fj)
      bv[fj] = bias[expert * DD + nb * EBN + wc * 64 + fj * 16 + l15];
#pragma unroll
    for (int fi = 0; fi < 4; ++fi) {
      int rl = wr * 64 + fi * 16 + lg * 4;
#pragma unroll
      for (int j = 0; j < 4; ++j) {
        int tok = tok_s[rl + j];
        float p = p_s[rl + j];
#pragma unroll
        for (int fj = 0; fj < 4; ++fj) {
          float v = (acc[fi][fj][j] + bv[fj]) * p;
          int col = nb * EBN + wc * 64 + fj * 16 + l15;
          atomicAdd(outp + (size_t)tok * DD + col, v);  // exactly 2 adds/elem, f32 add commutative -> deterministic
        }
      }
    }
  }
}

// ---------------- host ----------------

extern "C" void kernel_launch(void* const* d_in, const int* in_sizes, int n_in,
                              void* d_out, int out_size, void* d_ws, size_t ws_size,
                              hipStream_t stream) {
  const float* x = (const float*)d_in[0];
  const float* wp = (const float*)d_in[1];
  const float* sim = (const float*)d_in[2];
  const float* temp = (const float*)d_in[3];
  const float* w1 = (const float*)d_in[4];
  const float* b1 = (const float*)d_in[5];
  const float* w2 = (const float*)d_in[6];
  const float* b2 = (const float*)d_in[7];
  float* out = (float*)d_out;

  char* w = (char*)d_ws;
  size_t off = 0;
  auto alloc = [&](size_t sz) {
    char* p = w + off;
    off = (off + sz + 255) & ~(size_t)255;
    return p;
  };
  double* u = (double*)alloc((size_t)NEXP * DD * 8);
  double* snorm = (double*)alloc(NEXP * 8);
  float* nu_part = (float*)alloc((size_t)NTOK * 16 * 4);
  float* nu = (float*)alloc((size_t)NTOK * 4);
  int* t2e = (int*)alloc((size_t)NTOK * 2 * 4);
  float* t2p = (float*)alloc((size_t)NTOK * 2 * 4);
  int* meta = (int*)alloc(512);
  int* ptok = (int*)alloc((size_t)PAIR_CAP * 4);
  float* pp = (float*)alloc((size_t)PAIR_CAP * 4);
  ushort* xbf = (ushort*)alloc((size_t)NTOK * DD * 2);
  ushort* wpbf = (ushort*)alloc((size_t)DD * DD * 2);
  ushort* w1t = (ushort*)alloc((size_t)NEXP * DD * FF * 2);
  ushort* w2t = (ushort*)alloc((size_t)NEXP * DD * FF * 2);
  size_t havail = (ws_size > off) ? (ws_size - off) : 0;
  int G = (int)(havail / ((size_t)EBM * FF * 2));   // 1MB per tile of h
  if (G > TILES_MAX) G = TILES_MAX;
  if (G < 1) G = 1;
  ushort* h = (ushort*)(w + off);

  hipMemsetAsync(d_out, 0, (size_t)out_size * 4, stream);

  k_convert4<<<dim3(NTOK * DD / 4 / 256), 256, 0, stream>>>((const float4*)x, xbf, NTOK * DD / 4);
  k_convert4<<<dim3(DD * DD / 4 / 256), 256, 0, stream>>>((const float4*)wp, wpbf, DD * DD / 4);
  k_transpose<<<dim3(FF / 64, DD / 64, NEXP), 256, 0, stream>>>(w1, w1t, DD, FF);
  k_transpose<<<dim3(DD / 64, FF / 64, NEXP), 256, 0, stream>>>(w2, w2t, FF, DD);
  k_simnorm<<<1, 512, 0, stream>>>(sim, snorm);
  k_u<<<dim3(DD / 256, NEXP), 256, 0, stream>>>(wp, sim, snorm, u);
  gemm_x<0><<<dim3(NTOK / EBM, DD / EBN), 256, 0, stream>>>(
      xbf, wpbf, DD, DD, nullptr, nullptr, nullptr, nullptr, nu_part, nullptr, nullptr, 0);
  k_nured<<<dim3(NTOK / 256), 256, 0, stream>>>(nu_part, nu);
  k_gate<<<dim3(NTOK / 4), 256, 0, stream>>>(x, u, nu, temp, t2e, t2p);
  k_count<<<1, 256, 0, stream>>>(t2e, meta, ptok, pp);
  k_scatter<<<dim3(NTOK * 2 / 256), 256, 0, stream>>>(t2e, t2p, meta, ptok, pp);

  for (int t0 = 0; t0 < TILES_MAX; t0 += G) {
    int g = TILES_MAX - t0;
    if (g > G) g = G;
    gemm_x<1><<<dim3(g, FF / EBN), 256, 0, stream>>>(
        xbf, w1t, DD, FF, ptok, pp, meta, b1, nullptr, h, nullptr, t0);
    gemm_x<2><<<dim3(g, DD / EBN), 256, 0, stream>>>(
        h, w2t, FF, DD, ptok, pp, meta, b2, nullptr, nullptr, out, t0);
  }
}

// Round 4
// 616.272 us; speedup vs baseline: 1.1237x; 1.0248x over previous
//
#include <hip/hip_runtime.h>
#include <hip/hip_bf16.h>
#include <math.h>

// MoE MLP, MI355X. B=2,S=2048 -> NTOK=4096 tokens, D=1024, F=4096, E=8, top2.
#define NTOK 4096
#define DD 1024
#define FF 4096
#define NEXP 8
#define EBM 128          // expert-GEMM tile M
#define EBN 128          // expert-GEMM tile N
#define EBK 64           // expert-GEMM K-step
#define PAIR_CAP 9216    // 8192 pairs + 8*127 pad, rounded to 128
#define TILES_MAX 72     // PAIR_CAP / 128

typedef short bf16x8 __attribute__((ext_vector_type(8)));
typedef float f32x4 __attribute__((ext_vector_type(4)));

__device__ __forceinline__ ushort f2bf(float x) {
  unsigned u = __float_as_uint(x);
  unsigned r = (u + 0x7FFFu + ((u >> 16) & 1u)) >> 16;
  return (ushort)r;
}

__device__ __forceinline__ void async16(const void* g, void* l) {
  __builtin_amdgcn_global_load_lds(
      (const __attribute__((address_space(1))) char*)g,
      (__attribute__((address_space(3))) char*)l, 16, 0, 0);
}

// ---------------- small kernels ----------------

__global__ void k_convert4(const float4* __restrict__ s, ushort* __restrict__ d, int n4) {
  int i = blockIdx.x * 256 + threadIdx.x;
  if (i >= n4) return;
  float4 v = s[i];
  ushort4 o;
  o.x = f2bf(v.x); o.y = f2bf(v.y); o.z = f2bf(v.z); o.w = f2bf(v.w);
  *(ushort4*)(d + (size_t)i * 4) = o;
}

// src [E][R][C] f32 -> dst [E][C][R] bf16. 64x64 tiles, float4 in, ushort4 out.
__global__ void k_transpose(const float* __restrict__ src, ushort* __restrict__ dst,
                            int R, int C) {
  __shared__ float tile[64][65];
  int e = blockIdx.z;
  const float* s = src + (size_t)e * R * C;
  ushort* d = dst + (size_t)e * R * C;
  int c0 = blockIdx.x * 64, r0 = blockIdx.y * 64;
  int tid = threadIdx.x;           // 256
  int rr = tid >> 4, q4 = (tid & 15) * 4;
#pragma unroll
  for (int i = 0; i < 4; ++i) {
    int r = i * 16 + rr;
    float4 v = *(const float4*)&s[(size_t)(r0 + r) * C + c0 + q4];
    tile[r][q4 + 0] = v.x; tile[r][q4 + 1] = v.y;
    tile[r][q4 + 2] = v.z; tile[r][q4 + 3] = v.w;
  }
  __syncthreads();
#pragma unroll
  for (int i = 0; i < 4; ++i) {
    int c = i * 16 + rr;
    ushort4 o;
    o.x = f2bf(tile[q4 + 0][c]); o.y = f2bf(tile[q4 + 1][c]);
    o.z = f2bf(tile[q4 + 2][c]); o.w = f2bf(tile[q4 + 3][c]);
    *(ushort4*)&d[(size_t)(c0 + c) * R + r0 + q4] = o;
  }
}

__global__ void k_simnorm(const float* __restrict__ sim, double* __restrict__ snorm) {
  int wid = threadIdx.x >> 6, lane = threadIdx.x & 63;  // 8 waves = 8 experts
  double s = 0.0;
  for (int d = lane; d < DD; d += 64) { double v = sim[wid * DD + d]; s += v * v; }
#pragma unroll
  for (int m = 32; m; m >>= 1) s += __shfl_down(s, m);
  if (lane == 0) snorm[wid] = sqrt(s);
}

// u[e][d] = sum_o Wp[o][d]*sim[e][o] / max(||sim_e||,eps)    (f64)
__global__ void k_u(const float* __restrict__ wp, const float* __restrict__ sim,
                    const double* __restrict__ snorm, double* __restrict__ u) {
  int d = blockIdx.x * 256 + threadIdx.x;
  int e = blockIdx.y;
  double acc = 0.0;
#pragma unroll 8
  for (int o = 0; o < DD; ++o)
    acc += (double)wp[(size_t)o * DD + d] * (double)sim[e * DD + o];
  u[e * DD + d] = acc / fmax(snorm[e], 1e-12);
}

__global__ void k_nured(const float* __restrict__ part, float* __restrict__ nu) {
  int t = blockIdx.x * 256 + threadIdx.x;
  float s = 0.f;
#pragma unroll
  for (int i = 0; i < 16; ++i) s += part[t * 16 + i];
  nu[t] = s;
}

// per-token: n_e = x . u_e (f64), scores = n_e / (max(||proj||,eps)*T), top2 + softmax
__global__ void k_gate(const float* __restrict__ x, const double* __restrict__ u,
                       const float* __restrict__ nu, const float* __restrict__ temp,
                       int* __restrict__ t2e, float* __restrict__ t2p) {
  int wid = threadIdx.x >> 6, lane = threadIdx.x & 63;
  int t = blockIdx.x * 4 + wid;
  double acc[NEXP];
#pragma unroll
  for (int e = 0; e < NEXP; ++e) acc[e] = 0.0;
  for (int d = lane; d < DD; d += 64) {
    double xv = x[(size_t)t * DD + d];
#pragma unroll
    for (int e = 0; e < NEXP; ++e) acc[e] += xv * u[e * DD + d];
  }
#pragma unroll
  for (int e = 0; e < NEXP; ++e)
    for (int m = 32; m; m >>= 1) acc[e] += __shfl_down(acc[e], m);
  if (lane == 0) {
    double den = fmax(sqrt((double)nu[t]), 1e-12) * (double)temp[0];
    double s[NEXP];
#pragma unroll
    for (int e = 0; e < NEXP; ++e) s[e] = acc[e] / den;
    int e1 = 0; double v1 = s[0];
    for (int e = 1; e < NEXP; ++e) if (s[e] > v1) { v1 = s[e]; e1 = e; }
    int e2 = -1; double v2 = -1e300;
    for (int e = 0; e < NEXP; ++e) if (e != e1 && s[e] > v2) { v2 = s[e]; e2 = e; }
    double z = exp(v2 - v1);
    double inv = 1.0 / (1.0 + z);
    t2e[t * 2] = e1; t2e[t * 2 + 1] = e2;
    t2p[t * 2] = (float)inv; t2p[t * 2 + 1] = (float)(z * inv);
  }
}

// meta: [0..7]=cnt [8..16]=padded offsets [17]=ntiles [18..25]=cursors [26..]=tile_expert
__global__ void k_count(const int* __restrict__ t2e, int* __restrict__ meta,
                        int* __restrict__ ptok, float* __restrict__ pp) {
  __shared__ int cnt[NEXP];
  int tid = threadIdx.x;
  if (tid < NEXP) cnt[tid] = 0;
  __syncthreads();
  for (int i = tid; i < NTOK * 2; i += 256) atomicAdd(&cnt[t2e[i]], 1);
  __syncthreads();
  if (tid == 0) {
    int off = 0;
    for (int e = 0; e < NEXP; ++e) {
      meta[e] = cnt[e];
      meta[8 + e] = off;
      off += ((cnt[e] + EBM - 1) / EBM) * EBM;
    }
    meta[16] = off;
    meta[17] = off / EBM;
    for (int e = 0; e < NEXP; ++e) meta[18 + e] = 0;
    int ti = 0;
    for (int e = 0; e < NEXP; ++e) {
      int nt = (cnt[e] + EBM - 1) / EBM;
      for (int k = 0; k < nt; ++k) meta[26 + ti++] = e;
    }
  }
  for (int i = tid; i < PAIR_CAP; i += 256) { ptok[i] = 0; pp[i] = 0.f; }
}

__global__ void k_scatter(const int* __restrict__ t2e, const float* __restrict__ t2p,
                          int* __restrict__ meta, int* __restrict__ ptok,
                          float* __restrict__ pp) {
  int i = blockIdx.x * 256 + threadIdx.x;
  if (i >= NTOK * 2) return;
  int e = t2e[i];
  int slot = atomicAdd(&meta[18 + e], 1);
  int pos = meta[8 + e] + slot;
  ptok[pos] = i >> 1;
  pp[pos] = t2p[i];
}

// ---------------- unified GEMM: m97 structure + T1 XCD-chunked swizzle.
// 128x128 tile, BK=64, 4 waves (2x2, each 64x64 out), double-buffered 64KB LDS,
// global_load_lds(16), 2-barrier K-loop, 8-chunk XOR swizzle (pre-swizzled global
// source, conflict-free ds_read_b128). A,B both [rows][K] bf16 row-major.
// Grid is FLAT 1-D (g_tiles * nby). Swizzle: XCD k owns tiles [k*tpc,(k+1)*tpc),
// traversed tile-fastest -> chunk's A tiles stay L2-resident, each B panel read
// by consecutive resident blocks exactly once per XCD.
// EPI 0: proj -> per-row sum-of-squares into nu_part   (A=xbf, B=wpbf)
// EPI 1: gather-x @ W1t + b1, exact gelu -> h (bf16)   (A=xbf gathered, B=W1t[e])
// EPI 2: h @ W2t + b2, *p, atomicAdd into out          (A=h,  B=W2t[e])
template <int EPI>
__launch_bounds__(256, 2)
__global__ void gemm_x(const ushort* __restrict__ Abase, const ushort* __restrict__ Bbase,
                       int K, int Brows,
                       const int* __restrict__ pair_tok, const float* __restrict__ pair_p,
                       const int* __restrict__ meta, const float* __restrict__ bias,
                       float* __restrict__ nu_part, ushort* __restrict__ hout,
                       float* __restrict__ outp, int g_tiles, int nby, int tile0) {
  __shared__ ushort As[2][EBM * EBK];   // 2 x 16KB
  __shared__ ushort Bs[2][EBN * EBK];   // 2 x 16KB
  __shared__ int tok_s[EBM];
  __shared__ float p_s[EBM];

  const int tid = threadIdx.x;          // 256
  const int lane = tid & 63;
  const int wid = tid >> 6;             // 4 waves

  // ---- XCD-chunked swizzle (T1): requires g_tiles % 8 == 0, else identity ----
  int tile, nb;
  {
    int bid = blockIdx.x;
    if ((g_tiles & 7) == 0) {
      int tpc = g_tiles >> 3;
      int xcd = bid & 7, i = bid >> 3;
      tile = xcd * tpc + (i % tpc);     // tile-fastest within chunk
      nb = i / tpc;
    } else {
      tile = bid % g_tiles;
      nb = bid / g_tiles;
    }
  }
  tile += tile0;

  int expert = 0;
  if constexpr (EPI != 0) {
    if (tile >= meta[17]) return;
    expert = meta[26 + tile];
    if (tid < EBM) {
      int pr = tile * EBM + tid;
      tok_s[tid] = pair_tok[pr];
      p_s[tid] = pair_p[pr];
    }
    __syncthreads();
  }

  const char* Ac = (const char*)Abase;
  const char* Bc = (const char*)(Bbase + (size_t)expert * Brows * K);

  // tile = 1024 chunks of 16B; 4 groups of 256. chunk c: m=c>>3, cc=c&7.
  // global source pre-swizzled: cc ^= m&7  (LDS stays linear -> gload_lds legal).
  const char* asrc[4];
  const char* bsrc[4];
#pragma unroll
  for (int i = 0; i < 4; ++i) {
    int m = i * 32 + (tid >> 3), cc = tid & 7;
    int sw = (cc ^ (m & 7)) << 4;
    int arow;
    if constexpr (EPI == 1) arow = tok_s[m];
    else if constexpr (EPI == 2) arow = (tile - tile0) * EBM + m;
    else arow = tile * EBM + m;
    asrc[i] = Ac + (size_t)arow * K * 2 + sw;
    bsrc[i] = Bc + (size_t)(nb * EBN + m) * K * 2 + sw;
  }

  const int wr = wid >> 1, wc = wid & 1;     // 2x2 waves, each 64x64 of C
  const int l15 = lane & 15, lg = lane >> 4;

  f32x4 acc[4][4];
#pragma unroll
  for (int a = 0; a < 4; ++a)
#pragma unroll
    for (int b = 0; b < 4; ++b) acc[a][b] = (f32x4){0.f, 0.f, 0.f, 0.f};

  const int nk = K / EBK;

  // prologue stage -> buf 0   (dest = wave-uniform base; lanes append *16)
#pragma unroll
  for (int i = 0; i < 4; ++i) {
    async16(asrc[i], (char*)(&As[0][0]) + (i * 256 + wid * 64) * 16);
    async16(bsrc[i], (char*)(&Bs[0][0]) + (i * 256 + wid * 64) * 16);
  }

  for (int kt = 0; kt < nk; ++kt) {
    const int cur = kt & 1;
    __syncthreads();  // compiler drains vmcnt before barrier -> buf[cur] ready
    if (kt + 1 < nk) {
      const size_t ko = (size_t)(kt + 1) * EBK * 2;
#pragma unroll
      for (int i = 0; i < 4; ++i) {
        async16(asrc[i] + ko, (char*)(&As[cur ^ 1][0]) + (i * 256 + wid * 64) * 16);
        async16(bsrc[i] + ko, (char*)(&Bs[cur ^ 1][0]) + (i * 256 + wid * 64) * 16);
      }
    }
    const char* Ab = (const char*)(&As[cur][0]);
    const char* Bb = (const char*)(&Bs[cur][0]);
#pragma unroll
    for (int kk = 0; kk < 2; ++kk) {
      bf16x8 af[4], bfr[4];
#pragma unroll
      for (int fi = 0; fi < 4; ++fi) {
        int r = wr * 64 + fi * 16 + l15;
        int cidx = (kk * 4 + lg) ^ (l15 & 7);
        af[fi] = *(const bf16x8*)(Ab + r * 128 + cidx * 16);
      }
#pragma unroll
      for (int fj = 0; fj < 4; ++fj) {
        int r = wc * 64 + fj * 16 + l15;
        int cidx = (kk * 4 + lg) ^ (l15 & 7);
        bfr[fj] = *(const bf16x8*)(Bb + r * 128 + cidx * 16);
      }
#pragma unroll
      for (int fi = 0; fi < 4; ++fi)
#pragma unroll
        for (int fj = 0; fj < 4; ++fj)
          acc[fi][fj] =
              __builtin_amdgcn_mfma_f32_16x16x32_bf16(af[fi], bfr[fj], acc[fi][fj], 0, 0, 0);
    }
  }

  // ---------------- epilogue ----------------
  if constexpr (EPI == 0) {
    // per-row sum of squares over this block's 128 cols -> nu_part[row][nb*2+wc]
#pragma unroll
    for (int fi = 0; fi < 4; ++fi) {
#pragma unroll
      for (int j = 0; j < 4; ++j) {
        float s = 0.f;
#pragma unroll
        for (int fj = 0; fj < 4; ++fj) { float v = acc[fi][fj][j]; s += v * v; }
        s += __shfl_xor(s, 1); s += __shfl_xor(s, 2);
        s += __shfl_xor(s, 4); s += __shfl_xor(s, 8);
        if (l15 == 0) {
          int row = tile * EBM + wr * 64 + fi * 16 + lg * 4 + j;
          nu_part[row * 16 + nb * 2 + wc] = s;
        }
      }
    }
  } else if constexpr (EPI == 1) {
    float bv[4];
#pragma unroll
    for (int fj = 0; fj < 4; ++fj)
      bv[fj] = bias[expert * FF + nb * EBN + wc * 64 + fj * 16 + l15];
#pragma unroll
    for (int fi = 0; fi < 4; ++fi)
#pragma unroll
      for (int fj = 0; fj < 4; ++fj)
#pragma unroll
        for (int j = 0; j < 4; ++j) {
          float v = acc[fi][fj][j] + bv[fj];
          float g = 0.5f * v * (1.0f + erff(v * 0.70710678118654752f));  // exact gelu
          int rl = wr * 64 + fi * 16 + lg * 4 + j;
          size_t grow = (size_t)(tile - tile0) * EBM + rl;
          int col = nb * EBN + wc * 64 + fj * 16 + l15;
          hout[grow * FF + col] = f2bf(g);
        }
  } else {
    float bv[4];
#pragma unroll
    for (int fj = 0; fj < 4; ++fj)
      bv[fj] = bias[expert * DD + nb * EBN + wc * 64 + fj * 16 + l15];
#pragma unroll
    for (int fi = 0; fi < 4; ++fi) {
      int rl = wr * 64 + fi * 16 + lg * 4;
#pragma unroll
      for (int j = 0; j < 4; ++j) {
        int tok = tok_s[rl + j];
        float p = p_s[rl + j];
#pragma unroll
        for (int fj = 0; fj < 4; ++fj) {
          float v = (acc[fi][fj][j] + bv[fj]) * p;
          int col = nb * EBN + wc * 64 + fj * 16 + l15;
          atomicAdd(outp + (size_t)tok * DD + col, v);  // exactly 2 adds/elem, f32 add commutative -> deterministic
        }
      }
    }
  }
}

// ---------------- host ----------------

extern "C" void kernel_launch(void* const* d_in, const int* in_sizes, int n_in,
                              void* d_out, int out_size, void* d_ws, size_t ws_size,
                              hipStream_t stream) {
  const float* x = (const float*)d_in[0];
  const float* wp = (const float*)d_in[1];
  const float* sim = (const float*)d_in[2];
  const float* temp = (const float*)d_in[3];
  const float* w1 = (const float*)d_in[4];
  const float* b1 = (const float*)d_in[5];
  const float* w2 = (const float*)d_in[6];
  const float* b2 = (const float*)d_in[7];
  float* out = (float*)d_out;

  char* w = (char*)d_ws;
  size_t off = 0;
  auto alloc = [&](size_t sz) {
    char* p = w + off;
    off = (off + sz + 255) & ~(size_t)255;
    return p;
  };
  double* u = (double*)alloc((size_t)NEXP * DD * 8);
  double* snorm = (double*)alloc(NEXP * 8);
  float* nu_part = (float*)alloc((size_t)NTOK * 16 * 4);
  float* nu = (float*)alloc((size_t)NTOK * 4);
  int* t2e = (int*)alloc((size_t)NTOK * 2 * 4);
  float* t2p = (float*)alloc((size_t)NTOK * 2 * 4);
  int* meta = (int*)alloc(512);
  int* ptok = (int*)alloc((size_t)PAIR_CAP * 4);
  float* pp = (float*)alloc((size_t)PAIR_CAP * 4);
  ushort* xbf = (ushort*)alloc((size_t)NTOK * DD * 2);
  ushort* wpbf = (ushort*)alloc((size_t)DD * DD * 2);
  ushort* w1t = (ushort*)alloc((size_t)NEXP * DD * FF * 2);
  ushort* w2t = (ushort*)alloc((size_t)NEXP * DD * FF * 2);
  size_t havail = (ws_size > off) ? (ws_size - off) : 0;
  int G = (int)(havail / ((size_t)EBM * FF * 2));   // 1MB per tile of h
  if (G > TILES_MAX) G = TILES_MAX;
  if (G >= 8) G &= ~7;                              // keep swizzle-friendly multiple of 8
  if (G < 1) G = 1;
  ushort* h = (ushort*)(w + off);

  hipMemsetAsync(d_out, 0, (size_t)out_size * 4, stream);

  k_convert4<<<dim3(NTOK * DD / 4 / 256), 256, 0, stream>>>((const float4*)x, xbf, NTOK * DD / 4);
  k_convert4<<<dim3(DD * DD / 4 / 256), 256, 0, stream>>>((const float4*)wp, wpbf, DD * DD / 4);
  k_transpose<<<dim3(FF / 64, DD / 64, NEXP), 256, 0, stream>>>(w1, w1t, DD, FF);
  k_transpose<<<dim3(DD / 64, FF / 64, NEXP), 256, 0, stream>>>(w2, w2t, FF, DD);
  k_simnorm<<<1, 512, 0, stream>>>(sim, snorm);
  k_u<<<dim3(DD / 256, NEXP), 256, 0, stream>>>(wp, sim, snorm, u);
  gemm_x<0><<<dim3((NTOK / EBM) * (DD / EBN)), 256, 0, stream>>>(
      xbf, wpbf, DD, DD, nullptr, nullptr, nullptr, nullptr, nu_part, nullptr, nullptr,
      NTOK / EBM, DD / EBN, 0);
  k_nured<<<dim3(NTOK / 256), 256, 0, stream>>>(nu_part, nu);
  k_gate<<<dim3(NTOK / 4), 256, 0, stream>>>(x, u, nu, temp, t2e, t2p);
  k_count<<<1, 256, 0, stream>>>(t2e, meta, ptok, pp);
  k_scatter<<<dim3(NTOK * 2 / 256), 256, 0, stream>>>(t2e, t2p, meta, ptok, pp);

  for (int t0 = 0; t0 < TILES_MAX; t0 += G) {
    int g = TILES_MAX - t0;
    if (g > G) g = G;
    gemm_x<1><<<dim3(g * (FF / EBN)), 256, 0, stream>>>(
        xbf, w1t, DD, FF, ptok, pp, meta, b1, nullptr, h, nullptr, g, FF / EBN, t0);
    gemm_x<2><<<dim3(g * (DD / EBN)), 256, 0, stream>>>(
        h, w2t, FF, DD, ptok, pp, meta, b2, nullptr, nullptr, out, g, DD / EBN, t0);
  }
}